// Round 5
// baseline (368.757 us; speedup 1.0000x reference)
//
#include <hip/hip_runtime.h>
#include <hip/hip_cooperative_groups.h>
#include <math.h>

namespace cg = cooperative_groups;

#define Cn 256
#define Ln 256
#define Bn 2
#define H1 1024
#define NIDX 64
#define NREL 128
#define NCOMBO 16384
#define TROWS 32

typedef __attribute__((ext_vector_type(8))) short bf16x8;
typedef __attribute__((ext_vector_type(4))) float f32x4;
typedef unsigned int u32;

__device__ __forceinline__ float gelu_exact(float x) {
    return 0.5f * x * (1.0f + erff(x * 0.70710678118654752f));
}
__device__ __forceinline__ short f2bf(float f) {
    unsigned u = __float_as_uint(f);
    return (short)((u + 0x7fffu + ((u >> 16) & 1u)) >> 16);   // RNE
}

// ================= phase bodies (shared by mega + fallback) =================

// prep: gt in [0,32768) fc1 swizzle; [32768,65536) fc2 swizzle; then mod.
// fragment unit u = (c*8 + wave)*16 + nt*8 + ks; load = base + u*512 + lane*8.
__device__ __forceinline__ void do_prep(
    int gt, const float* __restrict__ c_BD, const float* __restrict__ ada_w,
    const float* __restrict__ ada_b, const float* __restrict__ fc1_w,
    const float* __restrict__ fc2_w, float* __restrict__ mod,
    short* __restrict__ fc1s, short* __restrict__ fc2s)
{
    if (gt < 32768) {
        // fc1: [1024][256]; row = gt>>5, col chunk cc = gt&31
        const int row = gt >> 5, cc = gt & 31;
        const int c = row >> 8, wv = (row >> 5) & 7, nt = (row >> 4) & 1, l15 = row & 15;
        const int ks = cc >> 2, quad = cc & 3;
        const int lane = quad * 16 + l15;
        const int u = (c * 8 + wv) * 16 + nt * 8 + ks;
        const float* s = fc1_w + (size_t)row * Cn + cc * 8;
        float4 v0 = *(const float4*)s;
        float4 v1 = *(const float4*)(s + 4);
        bf16x8 o;
        o[0] = f2bf(v0.x); o[1] = f2bf(v0.y); o[2] = f2bf(v0.z); o[3] = f2bf(v0.w);
        o[4] = f2bf(v1.x); o[5] = f2bf(v1.y); o[6] = f2bf(v1.z); o[7] = f2bf(v1.w);
        *(bf16x8*)(fc1s + (size_t)u * 512 + lane * 8) = o;
    } else if (gt < 65536) {
        // fc2: [256][1024]; row = t>>7, col chunk cc = t&127
        const int t2 = gt - 32768;
        const int row = t2 >> 7, cc = t2 & 127;
        const int wv = (row >> 5) & 7, nt = (row >> 4) & 1, l15 = row & 15;
        const int c = cc >> 5, ks = (cc >> 2) & 7, quad = cc & 3;
        const int lane = quad * 16 + l15;
        const int u = (c * 8 + wv) * 16 + nt * 8 + ks;
        const float* s = fc2_w + (size_t)row * H1 + cc * 8;
        float4 v0 = *(const float4*)s;
        float4 v1 = *(const float4*)(s + 4);
        bf16x8 o;
        o[0] = f2bf(v0.x); o[1] = f2bf(v0.y); o[2] = f2bf(v0.z); o[3] = f2bf(v0.w);
        o[4] = f2bf(v1.x); o[5] = f2bf(v1.y); o[6] = f2bf(v1.z); o[7] = f2bf(v1.w);
        *(bf16x8*)(fc2s + (size_t)u * 512 + lane * 8) = o;
    } else if (gt < 65536 + Bn * 3 * Cn) {
        int o = gt - 65536;
        int b = o / (3 * Cn);
        int j = o - b * (3 * Cn);
        const float* crow = c_BD + b * Cn;
        const float* wrow = ada_w + (size_t)j * Cn;
        float acc = 0.f;
        for (int k = 0; k < Cn; k += 4) {
            float4 cv = *(const float4*)(crow + k);
            float4 wv = *(const float4*)(wrow + k);
            acc += (cv.x / (1.f + expf(-cv.x))) * wv.x;
            acc += (cv.y / (1.f + expf(-cv.y))) * wv.y;
            acc += (cv.z / (1.f + expf(-cv.z))) * wv.z;
            acc += (cv.w / (1.f + expf(-cv.w))) * wv.w;
        }
        mod[o] = acc + ada_b[j];
    }
}

// table: LN + fc1/gelu + fc2 + gate for 32 combo rows (bid), 512 threads.
__device__ __forceinline__ void do_table(
    int bid, int tid,
    const float* __restrict__ embed_w, const float* __restrict__ pos_w,
    const float* __restrict__ ln_g, const float* __restrict__ ln_b,
    const short* __restrict__ fc1s, const float* __restrict__ fc1_b,
    const short* __restrict__ fc2s, const float* __restrict__ fc2_b,
    const float* __restrict__ mod, float* __restrict__ table,
    short (*h_lds)[264], short (*g_lds)[264])
{
    const int wave = tid >> 6;           // 0..7
    const int lane = tid & 63;
    const int quad = lane >> 4;
    const int l15  = lane & 15;

    const int base = bid * TROWS;
    const int b    = base >> 13;
    const int idx  = (base >> 7) & 63;
    const int rel0 = base & 127;

    const float* modb = mod + b * (3 * Cn);
    const float* erow = embed_w + (size_t)idx * Cn;

    // ---- LN phase: wave handles rows wave*4 .. wave*4+3, float4-vectorized
    {
        const int c0 = lane * 4;
        float4 ev = *(const float4*)(erow + c0);
        float4 sc = *(const float4*)(modb + Cn + c0);
        sc.x += 1.f; sc.y += 1.f; sc.z += 1.f; sc.w += 1.f;
        const float4 sh = *(const float4*)(modb + c0);
        const float4 lg = *(const float4*)(ln_g + c0);
        const float4 lb = *(const float4*)(ln_b + c0);
        #pragma unroll
        for (int r4 = 0; r4 < 4; ++r4) {
            const int rr = wave * 4 + r4;
            const float4 p = *(const float4*)(pos_w + (size_t)(rel0 + rr) * Cn + c0);
            float v0 = (ev.x + p.x) * sc.x + sh.x;
            float v1 = (ev.y + p.y) * sc.y + sh.y;
            float v2 = (ev.z + p.z) * sc.z + sh.z;
            float v3 = (ev.w + p.w) * sc.w + sh.w;
            float sum = v0 + v1 + v2 + v3;
            #pragma unroll
            for (int off = 32; off; off >>= 1) sum += __shfl_xor(sum, off, 64);
            const float mu = sum * (1.f / Cn);
            float t0 = v0 - mu, t1 = v1 - mu, t2 = v2 - mu, t3 = v3 - mu;
            float p2 = t0 * t0 + t1 * t1 + t2 * t2 + t3 * t3;
            #pragma unroll
            for (int off = 32; off; off >>= 1) p2 += __shfl_xor(p2, off, 64);
            const float rstd = rsqrtf(p2 * (1.f / Cn) + 1e-5f);
            short4 hq;
            hq.x = f2bf(t0 * rstd * lg.x + lb.x);
            hq.y = f2bf(t1 * rstd * lg.y + lb.y);
            hq.z = f2bf(t2 * rstd * lg.z + lb.z);
            hq.w = f2bf(t3 * rstd * lg.w + lb.w);
            *(short4*)(&h_lds[rr][c0]) = hq;
        }
    }
    __syncthreads();

    f32x4 acc2[2][2];
    #pragma unroll
    for (int mt = 0; mt < 2; ++mt)
        #pragma unroll
        for (int nt = 0; nt < 2; ++nt) acc2[mt][nt] = (f32x4){0.f, 0.f, 0.f, 0.f};

    for (int c = 0; c < 4; ++c) {
        f32x4 z[2][2];
        #pragma unroll
        for (int mt = 0; mt < 2; ++mt)
            #pragma unroll
            for (int nt = 0; nt < 2; ++nt) z[mt][nt] = (f32x4){0.f, 0.f, 0.f, 0.f};

        {
            const short* w1u = fc1s + (size_t)((c * 8 + wave) * 16) * 512 + lane * 8;
            bf16x8 wf[8][2];
            #pragma unroll
            for (int ks = 0; ks < 8; ++ks)
                #pragma unroll
                for (int nt = 0; nt < 2; ++nt)
                    wf[ks][nt] = *(const bf16x8*)(w1u + (nt * 8 + ks) * 512);
            #pragma unroll
            for (int ks = 0; ks < 8; ++ks) {
                const int k0 = ks * 32 + quad * 8;
                bf16x8 a0 = *(const bf16x8*)(&h_lds[l15][k0]);
                bf16x8 a1 = *(const bf16x8*)(&h_lds[16 + l15][k0]);
                #pragma unroll
                for (int nt = 0; nt < 2; ++nt) {
                    z[0][nt] = __builtin_amdgcn_mfma_f32_16x16x32_bf16(wf[ks][nt], a0, z[0][nt], 0, 0, 0);
                    z[1][nt] = __builtin_amdgcn_mfma_f32_16x16x32_bf16(wf[ks][nt], a1, z[1][nt], 0, 0, 0);
                }
            }
        }
        __syncthreads();   // waves done reading g_lds of prev c before rewrite

        #pragma unroll
        for (int mt = 0; mt < 2; ++mt) {
            #pragma unroll
            for (int nt = 0; nt < 2; ++nt) {
                const int cc = wave * 32 + nt * 16 + quad * 4;
                const float4 b4 = *(const float4*)(fc1_b + c * 256 + cc);
                short4 o;
                o.x = f2bf(gelu_exact(z[mt][nt][0] + b4.x));
                o.y = f2bf(gelu_exact(z[mt][nt][1] + b4.y));
                o.z = f2bf(gelu_exact(z[mt][nt][2] + b4.z));
                o.w = f2bf(gelu_exact(z[mt][nt][3] + b4.w));
                *(short4*)(&g_lds[mt * 16 + l15][cc]) = o;
            }
        }
        __syncthreads();

        {
            const short* w2u = fc2s + (size_t)((c * 8 + wave) * 16) * 512 + lane * 8;
            bf16x8 wf[8][2];
            #pragma unroll
            for (int ks = 0; ks < 8; ++ks)
                #pragma unroll
                for (int nt = 0; nt < 2; ++nt)
                    wf[ks][nt] = *(const bf16x8*)(w2u + (nt * 8 + ks) * 512);
            #pragma unroll
            for (int ks = 0; ks < 8; ++ks) {
                const int k0 = ks * 32 + quad * 8;
                bf16x8 a0 = *(const bf16x8*)(&g_lds[l15][k0]);
                bf16x8 a1 = *(const bf16x8*)(&g_lds[16 + l15][k0]);
                #pragma unroll
                for (int nt = 0; nt < 2; ++nt) {
                    acc2[0][nt] = __builtin_amdgcn_mfma_f32_16x16x32_bf16(wf[ks][nt], a0, acc2[0][nt], 0, 0, 0);
                    acc2[1][nt] = __builtin_amdgcn_mfma_f32_16x16x32_bf16(wf[ks][nt], a1, acc2[1][nt], 0, 0, 0);
                }
            }
        }
        // NOTE: no trailing barrier needed — the barrier after next gemm1
        // already orders gemm2 reads of g_lds before its rewrite.
    }

    // ---- epilogue: out = s + gate*(acc2 + b2), s recomputed, float4 stores
    #pragma unroll
    for (int mt = 0; mt < 2; ++mt) {
        const int row = mt * 16 + l15;
        const float* prow = pos_w + (size_t)(rel0 + row) * Cn;
        #pragma unroll
        for (int nt = 0; nt < 2; ++nt) {
            const int n0 = wave * 32 + nt * 16 + quad * 4;
            const float4 b4 = *(const float4*)(fc2_b + n0);
            const float4 g4 = *(const float4*)(modb + 2 * Cn + n0);
            const float4 sc = *(const float4*)(modb + Cn + n0);
            const float4 sh = *(const float4*)(modb + n0);
            const float4 e4 = *(const float4*)(erow + n0);
            const float4 p4 = *(const float4*)(prow + n0);
            float4 o;
            float s;
            s   = (e4.x + p4.x) * (1.f + sc.x) + sh.x;
            o.x = s + g4.x * (acc2[mt][nt][0] + b4.x);
            s   = (e4.y + p4.y) * (1.f + sc.y) + sh.y;
            o.y = s + g4.y * (acc2[mt][nt][1] + b4.y);
            s   = (e4.z + p4.z) * (1.f + sc.z) + sh.z;
            o.z = s + g4.z * (acc2[mt][nt][2] + b4.z);
            s   = (e4.w + p4.w) * (1.f + sc.w) + sh.w;
            o.w = s + g4.w * (acc2[mt][nt][3] + b4.w);
            *(float4*)(table + (size_t)(base + row) * Cn + n0) = o;
        }
    }
}

// gather: one (b,i) per block (512 threads); idx computed once for all 256 j.
__device__ __forceinline__ void do_gather(
    int bi, int tid,
    const float* __restrict__ x, const float* __restrict__ bins,
    const float* __restrict__ table, float* __restrict__ out,
    float* xs, float* bins_s, int* idx_s)
{
    const int b = bi >> 8;
    const int i = bi & 255;

    for (int t = tid; t < Ln * 3; t += 512) xs[t] = x[(size_t)b * Ln * 3 + t];
    if (tid < 63) bins_s[tid] = bins[tid];
    __syncthreads();

    if (tid < 256) {
        const int j = tid;
        float d0 = xs[3 * i]     - xs[3 * j];
        float d1 = xs[3 * i + 1] - xs[3 * j + 1];
        float d2 = xs[3 * i + 2] - xs[3 * j + 2];
        float d = d0 * d0 + d1 * d1 + d2 * d2;
        int v = 0;
        #pragma unroll
        for (int k = 0; k < 63; ++k) v += (bins_s[k] < d) ? 1 : 0;
        idx_s[j] = v;
    }
    __syncthreads();

    const int wave = tid >> 6;
    const int lane = tid & 63;
    float4* outp = (float4*)(out + (size_t)bi * Ln * Cn);
    const float4* tab4 = (const float4*)table;

    #pragma unroll
    for (int q = 0; q < 4; ++q) {
        float4 v[8];
        #pragma unroll
        for (int jj = 0; jj < 8; ++jj) {
            const int j = q * 64 + wave * 8 + jj;
            int rel = i - j;
            rel = (rel < -64 ? -64 : (rel > 63 ? 63 : rel)) + 64;
            size_t trow = (size_t)((b * NIDX + idx_s[j]) * NREL + rel) * (Cn / 4);
            v[jj] = tab4[trow + lane];
        }
        #pragma unroll
        for (int jj = 0; jj < 8; ++jj) {
            const int j = q * 64 + wave * 8 + jj;
            outp[(size_t)j * (Cn / 4) + lane] = v[jj];
        }
    }
}

// ================= mega kernel (cooperative) =================
__global__ __launch_bounds__(512, 4) void mega_kernel(
    const float* __restrict__ x, const float* __restrict__ bins,
    const float* __restrict__ c_BD, const float* __restrict__ ada_w,
    const float* __restrict__ ada_b, const float* __restrict__ fc1_w,
    const float* __restrict__ fc1_b, const float* __restrict__ fc2_w,
    const float* __restrict__ fc2_b, const float* __restrict__ embed_w,
    const float* __restrict__ pos_w, const float* __restrict__ ln_g,
    const float* __restrict__ ln_b, float* __restrict__ mod,
    short* __restrict__ fc1s, short* __restrict__ fc2s,
    float* __restrict__ table, float* __restrict__ out)
{
    __shared__ __align__(16) short h_lds[TROWS][264];
    __shared__ __align__(16) short g_lds[TROWS][264];
    __shared__ float xs[Ln * 3];
    __shared__ float bins_s[63];
    __shared__ int   idx_s[Ln];

    const int tid = threadIdx.x;
    const int bid = blockIdx.x;

    do_prep(bid * 512 + tid, c_BD, ada_w, ada_b, fc1_w, fc2_w, mod, fc1s, fc2s);
    cg::this_grid().sync();
    do_table(bid, tid, embed_w, pos_w, ln_g, ln_b, fc1s, fc1_b, fc2s, fc2_b,
             mod, table, h_lds, g_lds);
    cg::this_grid().sync();
    do_gather(bid, tid, x, bins, table, out, xs, bins_s, idx_s);
}

// ================= fallback (3 separate kernels) =================
__global__ __launch_bounds__(512) void prep_kernel(
    const float* __restrict__ c_BD, const float* __restrict__ ada_w,
    const float* __restrict__ ada_b, const float* __restrict__ fc1_w,
    const float* __restrict__ fc2_w, float* __restrict__ mod,
    short* __restrict__ fc1s, short* __restrict__ fc2s)
{
    do_prep(blockIdx.x * 512 + threadIdx.x, c_BD, ada_w, ada_b, fc1_w, fc2_w,
            mod, fc1s, fc2s);
}

__global__ __launch_bounds__(512, 4) void table_kernel(
    const float* __restrict__ embed_w, const float* __restrict__ pos_w,
    const float* __restrict__ ln_g, const float* __restrict__ ln_b,
    const short* __restrict__ fc1s, const float* __restrict__ fc1_b,
    const short* __restrict__ fc2s, const float* __restrict__ fc2_b,
    const float* __restrict__ mod, float* __restrict__ table)
{
    __shared__ __align__(16) short h_lds[TROWS][264];
    __shared__ __align__(16) short g_lds[TROWS][264];
    do_table(blockIdx.x, threadIdx.x, embed_w, pos_w, ln_g, ln_b, fc1s, fc1_b,
             fc2s, fc2_b, mod, table, h_lds, g_lds);
}

__global__ __launch_bounds__(512) void gather_std_kernel(
    const float* __restrict__ x, const float* __restrict__ bins,
    const float* __restrict__ table, float* __restrict__ out)
{
    __shared__ float xs[Ln * 3];
    __shared__ float bins_s[63];
    __shared__ int   idx_s[Ln];
    do_gather(blockIdx.x, threadIdx.x, x, bins, table, out, xs, bins_s, idx_s);
}

extern "C" void kernel_launch(void* const* d_in, const int* in_sizes, int n_in,
                              void* d_out, int out_size, void* d_ws, size_t ws_size,
                              hipStream_t stream) {
    const float* x_BLD   = (const float*)d_in[0];
    const float* c_BD    = (const float*)d_in[1];
    const float* embed_w = (const float*)d_in[2];
    const float* pos_w   = (const float*)d_in[3];
    const float* bins    = (const float*)d_in[4];
    const float* ada_w   = (const float*)d_in[5];
    const float* ada_b   = (const float*)d_in[6];
    const float* ln_g    = (const float*)d_in[7];
    const float* ln_b    = (const float*)d_in[8];
    const float* fc1_w   = (const float*)d_in[9];
    const float* fc1_b   = (const float*)d_in[10];
    const float* fc2_w   = (const float*)d_in[11];
    const float* fc2_b   = (const float*)d_in[12];
    float* out = (float*)d_out;

    char* ws = (char*)d_ws;
    float* mod   = (float*)ws;                               // 8 KB
    short* fc1s  = (short*)(ws + 8192);                      // 512 KB (fragment order)
    short* fc2s  = (short*)(ws + 8192 + 524288);             // 512 KB (fragment order)
    float* table = (float*)(ws + 8192 + 2 * 524288);         // 16 MB

    void* args[] = {
        (void*)&x_BLD, (void*)&bins, (void*)&c_BD, (void*)&ada_w, (void*)&ada_b,
        (void*)&fc1_w, (void*)&fc1_b, (void*)&fc2_w, (void*)&fc2_b,
        (void*)&embed_w, (void*)&pos_w, (void*)&ln_g, (void*)&ln_b,
        (void*)&mod, (void*)&fc1s, (void*)&fc2s, (void*)&table, (void*)&out
    };
    hipError_t e = hipLaunchCooperativeKernel((void*)mega_kernel, dim3(512),
                                              dim3(512), args, 0, stream);
    if (e != hipSuccess) {
        // fallback: proven 3-kernel path
        prep_kernel<<<131, 512, 0, stream>>>(c_BD, ada_w, ada_b, fc1_w, fc2_w,
                                             mod, fc1s, fc2s);
        table_kernel<<<NCOMBO / TROWS, 512, 0, stream>>>(
            embed_w, pos_w, ln_g, ln_b, fc1s, fc1_b, fc2s, fc2_b, mod, table);
        gather_std_kernel<<<Bn * Ln, 512, 0, stream>>>(x_BLD, bins, table, out);
    }
}

// Round 6
// 241.172 us; speedup vs baseline: 1.5290x; 1.5290x over previous
//
#include <hip/hip_runtime.h>
#include <math.h>

#define Cn 256
#define Ln 256
#define Bn 2
#define H1 1024
#define NIDX 64
#define NREL 128
#define NCOMBO 16384
#define TROWS 32

typedef __attribute__((ext_vector_type(8))) short bf16x8;
typedef __attribute__((ext_vector_type(4))) float f32x4;
typedef unsigned int u32;

__device__ __forceinline__ float gelu_exact(float x) {
    return 0.5f * x * (1.0f + erff(x * 0.70710678118654752f));
}
__device__ __forceinline__ short f2bf(float f) {
    unsigned u = __float_as_uint(f);
    return (short)((u + 0x7fffu + ((u >> 16) & 1u)) >> 16);   // RNE
}

// ---------------- prep ------------------------------------------------------
// blocks 0..127: fc1 fp32->bf16 in MFMA-fragment order
// blocks 128..255: fc2 likewise; blocks 256..261: mod = silu(c)@ada_w^T+ada_b
// fragment unit u = (c*8 + wave)*16 + nt*8 + ks; hot-load = base + u*512 + lane*8.
__global__ __launch_bounds__(256) void prep_kernel(
    const float* __restrict__ c_BD, const float* __restrict__ ada_w,
    const float* __restrict__ ada_b, const float* __restrict__ fc1_w,
    const float* __restrict__ fc2_w, float* __restrict__ mod,
    short* __restrict__ fc1s, short* __restrict__ fc2s)
{
    const int bid = blockIdx.x;
    const int tid = threadIdx.x;
    if (bid < 128) {
        const int t   = bid * 256 + tid;
        const int row = t >> 5;
        const int cc  = t & 31;
        const int c   = row >> 8, wv = (row >> 5) & 7, nt = (row >> 4) & 1, l15 = row & 15;
        const int ks  = cc >> 2, quad = cc & 3;
        const int lane = quad * 16 + l15;
        const int u   = (c * 8 + wv) * 16 + nt * 8 + ks;
        const float* s = fc1_w + (size_t)row * Cn + cc * 8;
        float4 v0 = *(const float4*)s;
        float4 v1 = *(const float4*)(s + 4);
        bf16x8 o;
        o[0] = f2bf(v0.x); o[1] = f2bf(v0.y); o[2] = f2bf(v0.z); o[3] = f2bf(v0.w);
        o[4] = f2bf(v1.x); o[5] = f2bf(v1.y); o[6] = f2bf(v1.z); o[7] = f2bf(v1.w);
        *(bf16x8*)(fc1s + (size_t)u * 512 + lane * 8) = o;
    } else if (bid < 256) {
        const int t   = (bid - 128) * 256 + tid;
        const int row = t >> 7;
        const int cc  = t & 127;
        const int wv  = (row >> 5) & 7, nt = (row >> 4) & 1, l15 = row & 15;
        const int c   = cc >> 5, ks = (cc >> 2) & 7, quad = cc & 3;
        const int lane = quad * 16 + l15;
        const int u   = (c * 8 + wv) * 16 + nt * 8 + ks;
        const float* s = fc2_w + (size_t)row * H1 + cc * 8;
        float4 v0 = *(const float4*)s;
        float4 v1 = *(const float4*)(s + 4);
        bf16x8 o;
        o[0] = f2bf(v0.x); o[1] = f2bf(v0.y); o[2] = f2bf(v0.z); o[3] = f2bf(v0.w);
        o[4] = f2bf(v1.x); o[5] = f2bf(v1.y); o[6] = f2bf(v1.z); o[7] = f2bf(v1.w);
        *(bf16x8*)(fc2s + (size_t)u * 512 + lane * 8) = o;
    } else {
        int o = (bid - 256) * 256 + tid;
        int b = o / (3 * Cn);
        int j = o - b * (3 * Cn);
        const float* crow = c_BD + b * Cn;
        const float* wrow = ada_w + (size_t)j * Cn;
        float acc = 0.f;
        for (int k = 0; k < Cn; k += 4) {
            float4 cv = *(const float4*)(crow + k);
            float4 wv = *(const float4*)(wrow + k);
            acc += (cv.x / (1.f + expf(-cv.x))) * wv.x;
            acc += (cv.y / (1.f + expf(-cv.y))) * wv.y;
            acc += (cv.z / (1.f + expf(-cv.z))) * wv.z;
            acc += (cv.w / (1.f + expf(-cv.w))) * wv.w;
        }
        mod[o] = acc + ada_b[j];
    }
}

// --- 8x K-step MFMA block: zz += W(frag-ordered) x A(lds rows) ---
__device__ __forceinline__ void gemm_frag(
    const short* __restrict__ wu, const short (*src)[264], int quad, int l15,
    f32x4 zz[2][2])
{
    #pragma unroll
    for (int ks = 0; ks < 8; ++ks) {
        const int k0 = ks * 32 + quad * 8;
        bf16x8 a0 = *(const bf16x8*)(&src[l15][k0]);
        bf16x8 a1 = *(const bf16x8*)(&src[16 + l15][k0]);
        #pragma unroll
        for (int nt = 0; nt < 2; ++nt) {
            bf16x8 w = *(const bf16x8*)(wu + (nt * 8 + ks) * 512);
            zz[0][nt] = __builtin_amdgcn_mfma_f32_16x16x32_bf16(w, a0, zz[0][nt], 0, 0, 0);
            zz[1][nt] = __builtin_amdgcn_mfma_f32_16x16x32_bf16(w, a1, zz[1][nt], 0, 0, 0);
        }
    }
}

__device__ __forceinline__ void gelu_store(
    const f32x4 zz[2][2], const float* __restrict__ fc1_b, int c,
    int wave, int quad, int l15, short (*dst)[264])
{
    #pragma unroll
    for (int mt = 0; mt < 2; ++mt) {
        #pragma unroll
        for (int nt = 0; nt < 2; ++nt) {
            const int cc = wave * 32 + nt * 16 + quad * 4;
            const float4 b4 = *(const float4*)(fc1_b + c * 256 + cc);
            short4 o;
            o.x = f2bf(gelu_exact(zz[mt][nt][0] + b4.x));
            o.y = f2bf(gelu_exact(zz[mt][nt][1] + b4.y));
            o.z = f2bf(gelu_exact(zz[mt][nt][2] + b4.z));
            o.w = f2bf(gelu_exact(zz[mt][nt][3] + b4.w));
            *(short4*)(&dst[mt * 16 + l15][cc]) = o;
        }
    }
}

// ---------------- table: LN + fc1/gelu + fc2 + gate, SW-pipelined ----------
// 512 threads (8 waves), 32 combo rows/block, grid=512 -> 2 blocks/CU.
// g_lds double-buffered: region {gemm2(c) || gemm1(c+1) || gelu(c+1)} runs
// between single barriers -> 32 MFMAs + both weight streams + gelu VALU
// co-scheduled (was 3 serial barrier-separated phases).
__global__ __launch_bounds__(512, 4) void table_kernel(
    const float* __restrict__ embed_w, const float* __restrict__ pos_w,
    const float* __restrict__ ln_g, const float* __restrict__ ln_b,
    const short* __restrict__ fc1s, const float* __restrict__ fc1_b,
    const short* __restrict__ fc2s, const float* __restrict__ fc2_b,
    const float* __restrict__ mod, float* __restrict__ table)
{
    __shared__ __align__(16) short h_lds[TROWS][264];      // 16.9 KB
    __shared__ __align__(16) short g_lds[2][TROWS][264];   // 33.8 KB

    const int tid  = threadIdx.x;
    const int wave = tid >> 6;           // 0..7
    const int lane = tid & 63;
    const int quad = lane >> 4;
    const int l15  = lane & 15;

    const int base = blockIdx.x * TROWS;
    const int b    = base >> 13;
    const int idx  = (base >> 7) & 63;
    const int rel0 = base & 127;

    const float* modb = mod + b * (3 * Cn);
    const float* erow = embed_w + (size_t)idx * Cn;

    // ---- LN phase: wave handles rows wave*4 .. wave*4+3, float4-vectorized
    {
        const int c0 = lane * 4;
        float4 ev = *(const float4*)(erow + c0);
        float4 sc = *(const float4*)(modb + Cn + c0);
        sc.x += 1.f; sc.y += 1.f; sc.z += 1.f; sc.w += 1.f;
        const float4 sh = *(const float4*)(modb + c0);
        const float4 lg = *(const float4*)(ln_g + c0);
        const float4 lb = *(const float4*)(ln_b + c0);
        #pragma unroll
        for (int r4 = 0; r4 < 4; ++r4) {
            const int rr = wave * 4 + r4;
            const float4 p = *(const float4*)(pos_w + (size_t)(rel0 + rr) * Cn + c0);
            float v0 = (ev.x + p.x) * sc.x + sh.x;
            float v1 = (ev.y + p.y) * sc.y + sh.y;
            float v2 = (ev.z + p.z) * sc.z + sh.z;
            float v3 = (ev.w + p.w) * sc.w + sh.w;
            float sum = v0 + v1 + v2 + v3;
            #pragma unroll
            for (int off = 32; off; off >>= 1) sum += __shfl_xor(sum, off, 64);
            const float mu = sum * (1.f / Cn);
            float t0 = v0 - mu, t1 = v1 - mu, t2 = v2 - mu, t3 = v3 - mu;
            float p2 = t0 * t0 + t1 * t1 + t2 * t2 + t3 * t3;
            #pragma unroll
            for (int off = 32; off; off >>= 1) p2 += __shfl_xor(p2, off, 64);
            const float rstd = rsqrtf(p2 * (1.f / Cn) + 1e-5f);
            short4 hq;
            hq.x = f2bf(t0 * rstd * lg.x + lb.x);
            hq.y = f2bf(t1 * rstd * lg.y + lb.y);
            hq.z = f2bf(t2 * rstd * lg.z + lb.z);
            hq.w = f2bf(t3 * rstd * lg.w + lb.w);
            *(short4*)(&h_lds[rr][c0]) = hq;
        }
    }
    __syncthreads();

    const size_t wtile = (size_t)(wave * 16) * 512 + lane * 8;   // per-c stride = 16*512*... (c*8 waves)
    f32x4 acc2[2][2];
    #pragma unroll
    for (int mt = 0; mt < 2; ++mt)
        #pragma unroll
        for (int nt = 0; nt < 2; ++nt) acc2[mt][nt] = (f32x4){0.f, 0.f, 0.f, 0.f};

    // prologue: gemm1(0) + gelu(0) -> g_lds[0]
    {
        f32x4 z[2][2];
        #pragma unroll
        for (int mt = 0; mt < 2; ++mt)
            #pragma unroll
            for (int nt = 0; nt < 2; ++nt) z[mt][nt] = (f32x4){0.f, 0.f, 0.f, 0.f};
        gemm_frag(fc1s + wtile, h_lds, quad, l15, z);
        gelu_store(z, fc1_b, 0, wave, quad, l15, g_lds[0]);
    }
    __syncthreads();

    // pipelined main loop: one barrier per iteration
    #pragma unroll
    for (int c = 0; c < 3; ++c) {
        gemm_frag(fc2s + (size_t)(c * 8) * 16 * 512 + wtile, g_lds[c & 1], quad, l15, acc2);
        f32x4 z[2][2];
        #pragma unroll
        for (int mt = 0; mt < 2; ++mt)
            #pragma unroll
            for (int nt = 0; nt < 2; ++nt) z[mt][nt] = (f32x4){0.f, 0.f, 0.f, 0.f};
        gemm_frag(fc1s + (size_t)((c + 1) * 8) * 16 * 512 + wtile, h_lds, quad, l15, z);
        gelu_store(z, fc1_b, c + 1, wave, quad, l15, g_lds[(c + 1) & 1]);
        __syncthreads();
    }
    gemm_frag(fc2s + (size_t)(3 * 8) * 16 * 512 + wtile, g_lds[1], quad, l15, acc2);

    // ---- epilogue: out = s + gate*(acc2 + b2), s recomputed, float4 stores
    #pragma unroll
    for (int mt = 0; mt < 2; ++mt) {
        const int row = mt * 16 + l15;
        const float* prow = pos_w + (size_t)(rel0 + row) * Cn;
        #pragma unroll
        for (int nt = 0; nt < 2; ++nt) {
            const int n0 = wave * 32 + nt * 16 + quad * 4;
            const float4 b4 = *(const float4*)(fc2_b + n0);
            const float4 g4 = *(const float4*)(modb + 2 * Cn + n0);
            const float4 sc = *(const float4*)(modb + Cn + n0);
            const float4 sh = *(const float4*)(modb + n0);
            const float4 e4 = *(const float4*)(erow + n0);
            const float4 p4 = *(const float4*)(prow + n0);
            float4 o;
            float s;
            s   = (e4.x + p4.x) * (1.f + sc.x) + sh.x;
            o.x = s + g4.x * (acc2[mt][nt][0] + b4.x);
            s   = (e4.y + p4.y) * (1.f + sc.y) + sh.y;
            o.y = s + g4.y * (acc2[mt][nt][1] + b4.y);
            s   = (e4.z + p4.z) * (1.f + sc.z) + sh.z;
            o.z = s + g4.z * (acc2[mt][nt][2] + b4.z);
            s   = (e4.w + p4.w) * (1.f + sc.w) + sh.w;
            o.w = s + g4.w * (acc2[mt][nt][3] + b4.w);
            *(float4*)(table + (size_t)(base + row) * Cn + n0) = o;
        }
    }
}

// ---------------- gather: out[b,i,j] = table[(b,idx,rel)] (R4 champion) ----
__global__ __launch_bounds__(256) void gather_kernel(
    const float* __restrict__ x, const float* __restrict__ bins,
    const float* __restrict__ table, float* __restrict__ out)
{
    __shared__ float xs[Ln * 3];
    __shared__ float bins_s[63];
    __shared__ int   idx_s[64];

    const int tid = threadIdx.x;
    const int blk = blockIdx.x;          // (b*256 + i)*4 + q
    const int q   = blk & 3;
    const int bi  = blk >> 2;
    const int b   = bi >> 8;
    const int i   = bi & 255;

    for (int t = tid; t < Ln * 3; t += 256) xs[t] = x[(size_t)b * Ln * 3 + t];
    if (tid < 63) bins_s[tid] = bins[tid];
    __syncthreads();

    if (tid < 64) {
        int j = q * 64 + tid;
        float d0 = xs[3 * i]     - xs[3 * j];
        float d1 = xs[3 * i + 1] - xs[3 * j + 1];
        float d2 = xs[3 * i + 2] - xs[3 * j + 2];
        float d = d0 * d0 + d1 * d1 + d2 * d2;
        int v = 0;
        #pragma unroll
        for (int k = 0; k < 63; ++k) v += (bins_s[k] < d) ? 1 : 0;
        idx_s[tid] = v;
    }
    __syncthreads();

    const int wave = tid >> 6;
    const int lane = tid & 63;
    float4* outp = (float4*)(out + (size_t)bi * Ln * Cn);
    const float4* tab4 = (const float4*)table;

    float4 v[16];
    #pragma unroll
    for (int jj = 0; jj < 16; ++jj) {
        int jl  = wave * 16 + jj;
        int j   = q * 64 + jl;
        int rel = i - j;
        rel = (rel < -64 ? -64 : (rel > 63 ? 63 : rel)) + 64;
        size_t trow = (size_t)((b * NIDX + idx_s[jl]) * NREL + rel) * (Cn / 4);
        v[jj] = tab4[trow + lane];
    }
    #pragma unroll
    for (int jj = 0; jj < 16; ++jj) {
        int j = q * 64 + wave * 16 + jj;
        outp[(size_t)j * (Cn / 4) + lane] = v[jj];
    }
}

extern "C" void kernel_launch(void* const* d_in, const int* in_sizes, int n_in,
                              void* d_out, int out_size, void* d_ws, size_t ws_size,
                              hipStream_t stream) {
    const float* x_BLD   = (const float*)d_in[0];
    const float* c_BD    = (const float*)d_in[1];
    const float* embed_w = (const float*)d_in[2];
    const float* pos_w   = (const float*)d_in[3];
    const float* bins    = (const float*)d_in[4];
    const float* ada_w   = (const float*)d_in[5];
    const float* ada_b   = (const float*)d_in[6];
    const float* ln_g    = (const float*)d_in[7];
    const float* ln_b    = (const float*)d_in[8];
    const float* fc1_w   = (const float*)d_in[9];
    const float* fc1_b   = (const float*)d_in[10];
    const float* fc2_w   = (const float*)d_in[11];
    const float* fc2_b   = (const float*)d_in[12];
    float* out = (float*)d_out;

    char* ws = (char*)d_ws;
    float* mod   = (float*)ws;                               // 8 KB
    short* fc1s  = (short*)(ws + 8192);                      // 512 KB (fragment order)
    short* fc2s  = (short*)(ws + 8192 + 524288);             // 512 KB (fragment order)
    float* table = (float*)(ws + 8192 + 2 * 524288);         // 16 MB

    prep_kernel<<<262, 256, 0, stream>>>(c_BD, ada_w, ada_b, fc1_w, fc2_w,
                                         mod, fc1s, fc2s);
    table_kernel<<<NCOMBO / TROWS, 512, 0, stream>>>(
        embed_w, pos_w, ln_g, ln_b, fc1s, fc1_b, fc2s, fc2_b, mod, table);
    gather_kernel<<<Bn * Ln * 4, 256, 0, stream>>>(x_BLD, bins, table, out);
}